// Round 1
// baseline (126.002 us; speedup 1.0000x reference)
//
#include <hip/hip_runtime.h>
#include <hip/hip_bf16.h>

#define N_FEATURES 4096
#define N_ACTIONS 4
#define N_CPA 10
#define N_CLAUSES 40
#define BATCH 16384
#define EPS 1e-8f
#define ACTIVE_THRESH 1e-6f

// ---------------- Kernel 1: per-clause d/cnt/negcnt ----------------
// grid = 40 blocks (one per clause), block = 256
__global__ void clause_kernel(const float* __restrict__ cw,
                              const float* __restrict__ ml,
                              const float* __restrict__ u,
                              const float* __restrict__ tptr,
                              float* __restrict__ d,      // [40][4096]
                              float* __restrict__ cnt,    // [40]
                              float* __restrict__ negcnt) // [40]
{
    const int c = blockIdx.x;
    const float temp = tptr[0] + EPS;
    const float inv_temp = 1.0f / temp;

    float pcount = 0.0f, ncount = 0.0f;
    for (int f = threadIdx.x; f < N_FEATURES; f += blockDim.x) {
        const int idx = f * N_CLAUSES + c;
        float uu = u[idx];
        float z = (logf(uu + EPS) - logf(1.0f - uu + EPS) + ml[idx]) * inv_temp;
        float s = 1.0f / (1.0f + expf(-z));
        float w = tanhf(cw[idx] * inv_temp) * s;
        bool active = fabsf(w) > ACTIVE_THRESH;
        bool pos = active && (w > 0.0f);
        bool neg = active && !(w > 0.0f);
        d[c * N_FEATURES + f] = pos ? 1.0f : (neg ? -1.0f : 0.0f);
        pcount += pos ? 1.0f : 0.0f;
        ncount += neg ? 1.0f : 0.0f;
    }

    // wave reduce
    #pragma unroll
    for (int off = 32; off; off >>= 1) {
        pcount += __shfl_down(pcount, off);
        ncount += __shfl_down(ncount, off);
    }
    __shared__ float sp[4], sn[4];
    const int wave = threadIdx.x >> 6;
    const int lane = threadIdx.x & 63;
    if (lane == 0) { sp[wave] = pcount; sn[wave] = ncount; }
    __syncthreads();
    if (threadIdx.x == 0) {
        float P = sp[0] + sp[1] + sp[2] + sp[3];
        float Nn = sn[0] + sn[1] + sn[2] + sn[3];
        cnt[c] = P + Nn;
        negcnt[c] = Nn;
    }
}

// ---------------- Kernel 2: fold into D planes + K ----------------
// grid = 64 blocks x 256 threads  (4096*4 = 16384 threads)
__global__ void dmat_kernel(const float* __restrict__ d,
                            const float* __restrict__ cnt,
                            const float* __restrict__ negcnt,
                            float* __restrict__ D,  // [4][4096], action-major planes
                            float* __restrict__ K)  // [4]
{
    const int idx = blockIdx.x * blockDim.x + threadIdx.x;
    const int f = idx & (N_FEATURES - 1);
    const int a = idx >> 12;
    float acc = 0.0f;
    #pragma unroll
    for (int j = 0; j < N_CPA; ++j) {
        const int c = a * N_CPA + j;
        float cn = cnt[c];
        if (cn > 0.0f) acc += d[c * N_FEATURES + f] / cn;
    }
    D[a * N_FEATURES + f] = acc;
    if (idx < N_ACTIONS) {
        float k = 0.0f;
        #pragma unroll
        for (int j = 0; j < N_CPA; ++j) {
            const int c = idx * N_CPA + j;
            float cn = cnt[c];
            k += (cn > 0.0f) ? (negcnt[c] / cn) : 1.0f;
        }
        K[idx] = k;
    }
}

// ---------------- Kernel 3: out = X @ D + K  (memory-bound GEMV) ----------------
// grid = 512 blocks x 256 threads; D staged in LDS (64 KiB -> 2 blocks/CU)
__global__ __launch_bounds__(256) void gemv_kernel(const float* __restrict__ x,
                                                   const float* __restrict__ D,
                                                   const float* __restrict__ K,
                                                   float* __restrict__ out)
{
    __shared__ float Dl[N_ACTIONS][N_FEATURES];   // 64 KiB
    __shared__ float Ks[N_ACTIONS];

    // cooperative load of D: 16384 floats = 4096 float4
    {
        const float4* D4 = (const float4*)D;
        float4* Dl4 = (float4*)&Dl[0][0];
        for (int i = threadIdx.x; i < N_ACTIONS * N_FEATURES / 4; i += blockDim.x)
            Dl4[i] = D4[i];
        if (threadIdx.x < N_ACTIONS) Ks[threadIdx.x] = K[threadIdx.x];
    }
    __syncthreads();

    const int wave = threadIdx.x >> 6;
    const int lane = threadIdx.x & 63;
    const int gwave = blockIdx.x * 4 + wave;
    const int nwaves = gridDim.x * 4;

    const float4* Dl0 = (const float4*)Dl[0];
    const float4* Dl1 = (const float4*)Dl[1];
    const float4* Dl2 = (const float4*)Dl[2];
    const float4* Dl3 = (const float4*)Dl[3];

    for (int b = gwave; b < BATCH; b += nwaves) {
        const float4* xr = (const float4*)(x + (size_t)b * N_FEATURES);
        float a0 = 0.0f, a1 = 0.0f, a2 = 0.0f, a3 = 0.0f;
        #pragma unroll
        for (int j = 0; j < N_FEATURES / 4 / 64; ++j) {   // 16 iterations
            const int f4 = lane + j * 64;
            float4 xv = xr[f4];
            float4 d0 = Dl0[f4];
            float4 d1 = Dl1[f4];
            float4 d2 = Dl2[f4];
            float4 d3 = Dl3[f4];
            a0 += xv.x * d0.x + xv.y * d0.y + xv.z * d0.z + xv.w * d0.w;
            a1 += xv.x * d1.x + xv.y * d1.y + xv.z * d1.z + xv.w * d1.w;
            a2 += xv.x * d2.x + xv.y * d2.y + xv.z * d2.z + xv.w * d2.w;
            a3 += xv.x * d3.x + xv.y * d3.y + xv.z * d3.z + xv.w * d3.w;
        }
        // wave reduction (64 lanes)
        #pragma unroll
        for (int off = 32; off; off >>= 1) {
            a0 += __shfl_down(a0, off);
            a1 += __shfl_down(a1, off);
            a2 += __shfl_down(a2, off);
            a3 += __shfl_down(a3, off);
        }
        if (lane == 0) {
            float4 o;
            o.x = a0 + Ks[0];
            o.y = a1 + Ks[1];
            o.z = a2 + Ks[2];
            o.w = a3 + Ks[3];
            ((float4*)out)[b] = o;
        }
    }
}

extern "C" void kernel_launch(void* const* d_in, const int* in_sizes, int n_in,
                              void* d_out, int out_size, void* d_ws, size_t ws_size,
                              hipStream_t stream) {
    const float* features = (const float*)d_in[0];
    const float* cw       = (const float*)d_in[1];
    const float* ml       = (const float*)d_in[2];
    const float* u        = (const float*)d_in[3];
    const float* tptr     = (const float*)d_in[4];
    float* out = (float*)d_out;

    // workspace layout (floats)
    float* ws = (float*)d_ws;
    float* d_buf   = ws;                                   // 40*4096
    float* cnt     = d_buf + N_CLAUSES * N_FEATURES;       // 40
    float* negcnt  = cnt + N_CLAUSES;                      // 40
    float* Dmat    = negcnt + N_CLAUSES;                   // 4*4096 (16B-aligned: offset 163920*4 bytes)
    float* K       = Dmat + N_ACTIONS * N_FEATURES;        // 4

    clause_kernel<<<N_CLAUSES, 256, 0, stream>>>(cw, ml, u, tptr, d_buf, cnt, negcnt);
    dmat_kernel<<<(N_ACTIONS * N_FEATURES) / 256, 256, 0, stream>>>(d_buf, cnt, negcnt, Dmat, K);
    gemv_kernel<<<512, 256, 0, stream>>>(features, Dmat, K, out);
}

// Round 3
// 63.970 us; speedup vs baseline: 1.9697x; 1.9697x over previous
//
#include <hip/hip_runtime.h>
#include <hip/hip_bf16.h>

#define N_FEATURES 4096
#define N_ACTIONS 4
#define N_CPA 10
#define N_CLAUSES 40
#define BATCH 16384
#define EPS 1e-8f
#define ACTIVE_THRESH 1e-6f

// ---------------- Kernel 1: per-element w -> d (f-major), counts via LDS atomics ----
// grid = 160 blocks x 256 threads, each thread handles 4 consecutive elements (float4)
__global__ void clause_kernel(const float* __restrict__ cw,
                              const float* __restrict__ ml,
                              const float* __restrict__ u,
                              const float* __restrict__ tptr,
                              float* __restrict__ d,      // [4096][40] f-major
                              float* __restrict__ cnt,    // [40] (pre-zeroed; cnt = pos+neg)
                              float* __restrict__ negcnt) // [40] (pre-zeroed)
{
    __shared__ float sp[N_CLAUSES], sn[N_CLAUSES];
    if (threadIdx.x < N_CLAUSES) { sp[threadIdx.x] = 0.0f; sn[threadIdx.x] = 0.0f; }
    __syncthreads();

    const float temp = tptr[0] + EPS;
    const float invt = 1.0f / temp;

    const int i4 = blockIdx.x * blockDim.x + threadIdx.x;   // float4 index, 0..40959
    const float4 u4  = ((const float4*)u)[i4];
    const float4 ml4 = ((const float4*)ml)[i4];
    const float4 cw4 = ((const float4*)cw)[i4];

    const float uu[4] = {u4.x, u4.y, u4.z, u4.w};
    const float mm[4] = {ml4.x, ml4.y, ml4.z, ml4.w};
    const float ww[4] = {cw4.x, cw4.y, cw4.z, cw4.w};
    float dv[4];

    #pragma unroll
    for (int e = 0; e < 4; ++e) {
        float z = (logf(uu[e] + EPS) - logf(1.0f - uu[e] + EPS) + mm[e]) * invt;
        float s = 1.0f / (1.0f + expf(-z));
        float w = tanhf(ww[e] * invt) * s;
        bool active = fabsf(w) > ACTIVE_THRESH;
        bool pos = active && (w > 0.0f);
        bool neg = active && !(w > 0.0f);
        dv[e] = pos ? 1.0f : (neg ? -1.0f : 0.0f);
        int c = (i4 * 4 + e) % N_CLAUSES;
        if (pos) atomicAdd(&sp[c], 1.0f);
        if (neg) atomicAdd(&sn[c], 1.0f);
    }
    ((float4*)d)[i4] = make_float4(dv[0], dv[1], dv[2], dv[3]);

    __syncthreads();
    if (threadIdx.x < N_CLAUSES) {
        float p = sp[threadIdx.x], n = sn[threadIdx.x];
        // cnt = total active literal count (pos + neg); negcnt = neg only.
        if (p + n != 0.0f) atomicAdd(&cnt[threadIdx.x], p + n);
        if (n != 0.0f)     atomicAdd(&negcnt[threadIdx.x], n);
    }
}

// ---------------- Kernel 2: fold into D planes (action-major) + K ----------------
// grid = 64 blocks x 256 threads (16384 threads)
__global__ void dmat_kernel(const float* __restrict__ d,   // [4096][40] f-major
                            const float* __restrict__ cnt,
                            const float* __restrict__ negcnt,
                            float* __restrict__ D,  // [4][4096]
                            float* __restrict__ K)  // [4]
{
    const int idx = blockIdx.x * blockDim.x + threadIdx.x;
    const int f = idx & (N_FEATURES - 1);
    const int a = idx >> 12;
    float acc = 0.0f;
    #pragma unroll
    for (int j = 0; j < N_CPA; ++j) {
        const int c = a * N_CPA + j;
        float cn = cnt[c];
        float inv = (cn > 0.0f) ? (1.0f / cn) : 0.0f;
        acc += d[f * N_CLAUSES + c] * inv;
    }
    D[a * N_FEATURES + f] = acc;
    if (idx < N_ACTIONS) {
        float k = 0.0f;
        #pragma unroll
        for (int j = 0; j < N_CPA; ++j) {
            const int c = idx * N_CPA + j;
            float cn = cnt[c];
            k += (cn > 0.0f) ? (negcnt[c] / cn) : 1.0f;
        }
        K[idx] = k;
    }
}

// ---------------- Kernel 3: out = X @ D + K, register-resident D ----------------
// block = 256 threads; thread owns 16 features (4 float4 chunks at stride 1024).
// grid = 2048 blocks x 8 rows each; rows processed 2 at a time (8 loads in flight/thread).
#define ROWS_PER_BLOCK 8
#define RG 2

__global__ __launch_bounds__(256) void gemv_kernel(const float* __restrict__ x,
                                                   const float* __restrict__ D,
                                                   const float* __restrict__ K,
                                                   float* __restrict__ out)
{
    const int tid  = threadIdx.x;
    const int wave = tid >> 6;
    const int lane = tid & 63;

    __shared__ float red[4][RG * N_ACTIONS];  // [wave][r*4+a]
    __shared__ float Ks[N_ACTIONS];

    // register-resident D fragment: [chunk][action] float4 (64 VGPRs)
    float4 Dr[4][4];
    #pragma unroll
    for (int c = 0; c < 4; ++c)
        #pragma unroll
        for (int a = 0; a < 4; ++a)
            Dr[c][a] = ((const float4*)(D + a * N_FEATURES))[c * 256 + tid];
    if (tid < N_ACTIONS) Ks[tid] = K[tid];
    __syncthreads();

    const int rb = blockIdx.x * ROWS_PER_BLOCK;

    for (int g = 0; g < ROWS_PER_BLOCK / RG; ++g) {
        // issue all loads first (8 independent global_load_dwordx4 per thread)
        float4 xv[RG][4];
        #pragma unroll
        for (int r = 0; r < RG; ++r) {
            const float4* xr = (const float4*)(x + (size_t)(rb + g * RG + r) * N_FEATURES);
            #pragma unroll
            for (int c = 0; c < 4; ++c)
                xv[r][c] = xr[c * 256 + tid];
        }

        float accf[RG * 4];
        #pragma unroll
        for (int v = 0; v < RG * 4; ++v) accf[v] = 0.0f;

        #pragma unroll
        for (int r = 0; r < RG; ++r)
            #pragma unroll
            for (int c = 0; c < 4; ++c) {
                const float4 xvv = xv[r][c];
                #pragma unroll
                for (int a = 0; a < 4; ++a) {
                    accf[r * 4 + a] += xvv.x * Dr[c][a].x + xvv.y * Dr[c][a].y
                                     + xvv.z * Dr[c][a].z + xvv.w * Dr[c][a].w;
                }
            }

        // butterfly wave reduction of the 8 values
        #pragma unroll
        for (int off = 32; off; off >>= 1)
            #pragma unroll
            for (int v = 0; v < RG * 4; ++v)
                accf[v] += __shfl_xor(accf[v], off);

        // lane v (v < 8) carries value v to LDS (compile-time indexed select)
        float myv = accf[0];
        #pragma unroll
        for (int v = 1; v < RG * 4; ++v)
            if (lane == v) myv = accf[v];
        if (lane < RG * 4) red[wave][lane] = myv;
        __syncthreads();

        if (tid < RG * 4) {
            float s = red[0][tid] + red[1][tid] + red[2][tid] + red[3][tid];
            const int r = tid >> 2;
            const int a = tid & 3;
            const int row = rb + g * RG + r;
            out[row * N_ACTIONS + a] = s + Ks[a];
        }
        __syncthreads();
    }
}

extern "C" void kernel_launch(void* const* d_in, const int* in_sizes, int n_in,
                              void* d_out, int out_size, void* d_ws, size_t ws_size,
                              hipStream_t stream) {
    const float* features = (const float*)d_in[0];
    const float* cw       = (const float*)d_in[1];
    const float* ml       = (const float*)d_in[2];
    const float* u        = (const float*)d_in[3];
    const float* tptr     = (const float*)d_in[4];
    float* out = (float*)d_out;

    // workspace layout (floats)
    float* ws = (float*)d_ws;
    float* d_buf   = ws;                                   // 4096*40 (f-major)
    float* cnt     = d_buf + N_CLAUSES * N_FEATURES;       // 40
    float* negcnt  = cnt + N_CLAUSES;                      // 40
    float* Dmat    = negcnt + N_CLAUSES;                   // 4*4096 (offset 163920 floats, 16B aligned)
    float* K       = Dmat + N_ACTIONS * N_FEATURES;        // 4

    // zero the atomic accumulators each call (graph-capture-safe async memset)
    hipMemsetAsync(cnt, 0, 2 * N_CLAUSES * sizeof(float), stream);

    clause_kernel<<<(N_CLAUSES * N_FEATURES) / (256 * 4), 256, 0, stream>>>(
        cw, ml, u, tptr, d_buf, cnt, negcnt);
    dmat_kernel<<<(N_ACTIONS * N_FEATURES) / 256, 256, 0, stream>>>(
        d_buf, cnt, negcnt, Dmat, K);
    gemv_kernel<<<BATCH / ROWS_PER_BLOCK, 256, 0, stream>>>(features, Dmat, K, out);
}

// Round 4
// 60.419 us; speedup vs baseline: 2.0855x; 1.0588x over previous
//
#include <hip/hip_runtime.h>
#include <hip/hip_bf16.h>

#define N_FEATURES 4096
#define N_ACTIONS 4
#define N_CPA 10
#define N_CLAUSES 40
#define BATCH 16384
#define EPS 1e-8f
#define ACTIVE_THRESH 1e-6f

typedef float f4v __attribute__((ext_vector_type(4)));

// ---------------- Kernel 1: per-clause d/cnt/negcnt (no atomics, no memset) -------
// grid = 40 blocks (one per clause), block = 512
__global__ void clause_kernel(const float* __restrict__ cw,
                              const float* __restrict__ ml,
                              const float* __restrict__ u,
                              const float* __restrict__ tptr,
                              float* __restrict__ d,      // [40][4096] c-major
                              float* __restrict__ cnt,    // [40]
                              float* __restrict__ negcnt) // [40]
{
    const int c = blockIdx.x;
    const float temp = tptr[0] + EPS;
    const float invt = 1.0f / temp;

    float pcount = 0.0f, ncount = 0.0f;
    for (int f = threadIdx.x; f < N_FEATURES; f += 512) {
        const int idx = f * N_CLAUSES + c;
        float uu = u[idx];
        // log(u+eps) - log(1-u+eps) == log((u+eps)/(1-u+eps))
        float z = (__logf((uu + EPS) / (1.0f - uu + EPS)) + ml[idx]) * invt;
        float s = 1.0f / (1.0f + __expf(-z));
        float w = tanhf(cw[idx] * invt) * s;
        bool active = fabsf(w) > ACTIVE_THRESH;
        bool pos = active && (w > 0.0f);
        bool neg = active && !(w > 0.0f);
        d[c * N_FEATURES + f] = pos ? 1.0f : (neg ? -1.0f : 0.0f);
        pcount += pos ? 1.0f : 0.0f;
        ncount += neg ? 1.0f : 0.0f;
    }

    #pragma unroll
    for (int off = 32; off; off >>= 1) {
        pcount += __shfl_down(pcount, off);
        ncount += __shfl_down(ncount, off);
    }
    __shared__ float sp[8], sn[8];
    const int wave = threadIdx.x >> 6;
    const int lane = threadIdx.x & 63;
    if (lane == 0) { sp[wave] = pcount; sn[wave] = ncount; }
    __syncthreads();
    if (threadIdx.x == 0) {
        float P = 0.0f, Nn = 0.0f;
        #pragma unroll
        for (int w8 = 0; w8 < 8; ++w8) { P += sp[w8]; Nn += sn[w8]; }
        cnt[c] = P + Nn;
        negcnt[c] = Nn;
    }
}

// ---------------- Kernel 2: fold into D planes (action-major) + K ----------------
// grid = 64 blocks x 256 threads
__global__ void dmat_kernel(const float* __restrict__ d,   // [40][4096] c-major
                            const float* __restrict__ cnt,
                            const float* __restrict__ negcnt,
                            float* __restrict__ D,  // [4][4096]
                            float* __restrict__ K)  // [4]
{
    const int idx = blockIdx.x * blockDim.x + threadIdx.x;
    const int f = idx & (N_FEATURES - 1);
    const int a = idx >> 12;
    float acc = 0.0f;
    #pragma unroll
    for (int j = 0; j < N_CPA; ++j) {
        const int c = a * N_CPA + j;
        float cn = cnt[c];
        float inv = (cn > 0.0f) ? (1.0f / cn) : 0.0f;
        acc += d[c * N_FEATURES + f] * inv;
    }
    D[a * N_FEATURES + f] = acc;
    if (idx < N_ACTIONS) {
        float k = 0.0f;
        #pragma unroll
        for (int j = 0; j < N_CPA; ++j) {
            const int c = idx * N_CPA + j;
            float cn = cnt[c];
            k += (cn > 0.0f) ? (negcnt[c] / cn) : 1.0f;
        }
        K[idx] = k;
    }
}

// ---------------- Kernel 3: out = X @ D + K, barrier-free main loop ----------------
// block = 256 threads covers a full 4096-feature row (thread: 4 float4 chunks @ stride 1024).
// 8 rows per block, 32 accumulators/thread, double-buffered row loads, ONE reduce tail.
#define RPB 8

__global__ __launch_bounds__(256, 3) void gemv_kernel(const float* __restrict__ x,
                                                      const float* __restrict__ D,
                                                      const float* __restrict__ K,
                                                      float* __restrict__ out)
{
    const int tid  = threadIdx.x;
    const int wave = tid >> 6;
    const int lane = tid & 63;

    __shared__ float red[4][32];

    // register-resident D fragment: [chunk][action] float4 (64 VGPRs)
    f4v Dr[4][4];
    #pragma unroll
    for (int c = 0; c < 4; ++c)
        #pragma unroll
        for (int a = 0; a < 4; ++a)
            Dr[c][a] = *(const f4v*)(D + a * N_FEATURES + (c * 256 + tid) * 4);

    const int rb = blockIdx.x * RPB;
    const f4v* xrow = (const f4v*)(x + (size_t)rb * N_FEATURES);

    float acc[RPB][4];
    #pragma unroll
    for (int r = 0; r < RPB; ++r)
        #pragma unroll
        for (int a = 0; a < 4; ++a) acc[r][a] = 0.0f;

    // double-buffered x loads: issue row r+1 before consuming row r
    f4v xv[2][4];
    #pragma unroll
    for (int c = 0; c < 4; ++c)
        xv[0][c] = __builtin_nontemporal_load(&xrow[c * 256 + tid]);

    #pragma unroll
    for (int r = 0; r < RPB; ++r) {
        const int cur = r & 1, nxt = cur ^ 1;
        if (r + 1 < RPB) {
            #pragma unroll
            for (int c = 0; c < 4; ++c)
                xv[nxt][c] = __builtin_nontemporal_load(&xrow[(r + 1) * 1024 + c * 256 + tid]);
        }
        #pragma unroll
        for (int c = 0; c < 4; ++c) {
            const f4v xc = xv[cur][c];
            #pragma unroll
            for (int a = 0; a < 4; ++a)
                acc[r][a] += xc.x * Dr[c][a].x + xc.y * Dr[c][a].y
                           + xc.z * Dr[c][a].z + xc.w * Dr[c][a].w;
        }
    }

    // single reduce tail: butterfly all 32 values across the wave (replicates to all lanes)
    #pragma unroll
    for (int off = 32; off; off >>= 1)
        #pragma unroll
        for (int r = 0; r < RPB; ++r)
            #pragma unroll
            for (int a = 0; a < 4; ++a)
                acc[r][a] += __shfl_xor(acc[r][a], off);

    // lane v (v<32) carries value v = r*4+a (compile-time-indexed select)
    float myv = acc[0][0];
    #pragma unroll
    for (int v = 1; v < 32; ++v)
        if (lane == v) myv = acc[v >> 2][v & 3];
    if (lane < 32) red[wave][lane] = myv;
    __syncthreads();

    if (tid < 32) {
        float s = red[0][tid] + red[1][tid] + red[2][tid] + red[3][tid];
        out[rb * N_ACTIONS + tid] = s + K[tid & 3];   // 32 consecutive floats, coalesced
    }
}

extern "C" void kernel_launch(void* const* d_in, const int* in_sizes, int n_in,
                              void* d_out, int out_size, void* d_ws, size_t ws_size,
                              hipStream_t stream) {
    const float* features = (const float*)d_in[0];
    const float* cw       = (const float*)d_in[1];
    const float* ml       = (const float*)d_in[2];
    const float* u        = (const float*)d_in[3];
    const float* tptr     = (const float*)d_in[4];
    float* out = (float*)d_out;

    // workspace layout (floats)
    float* ws = (float*)d_ws;
    float* d_buf   = ws;                                   // 40*4096 (c-major)
    float* cnt     = d_buf + N_CLAUSES * N_FEATURES;       // 40
    float* negcnt  = cnt + N_CLAUSES;                      // 40
    float* Dmat    = negcnt + N_CLAUSES;                   // 4*4096 (offset 163920 floats, 16B aligned)
    float* K       = Dmat + N_ACTIONS * N_FEATURES;        // 4

    clause_kernel<<<N_CLAUSES, 512, 0, stream>>>(cw, ml, u, tptr, d_buf, cnt, negcnt);
    dmat_kernel<<<(N_ACTIONS * N_FEATURES) / 256, 256, 0, stream>>>(d_buf, cnt, negcnt, Dmat, K);
    gemv_kernel<<<BATCH / RPB, 256, 0, stream>>>(features, Dmat, K, out);
}